// Round 8
// baseline (152.617 us; speedup 1.0000x reference)
//
#include <hip/hip_runtime.h>
#include <math.h>

#define D_MODEL 4096
#define N_EXP   64

typedef _Float16 half8 __attribute__((ext_vector_type(8)));
typedef float    f32x4 __attribute__((ext_vector_type(4)));

// ---------------------------------------------------------------------------
// Prep: W[64][4096] fp32 -> fragment-ordered fp16 hi/lo arrays (in d_ws).
// Ws = W*64; hi = fp16(Ws); lo = fp16((Ws-hi)*4096). Fragment order:
// element (kstep,nt,lane,j) at ((kstep*4+nt)*64+lane)*8+j, expert
// e = nt*16+(lane&15), k = kstep*32+(lane>>4)*8+j. (Verified R4-R7.)
// ---------------------------------------------------------------------------
__global__ __launch_bounds__(256)
void wprep_kernel(const float* __restrict__ W,
                  _Float16* __restrict__ whf, _Float16* __restrict__ wlf) {
    const int gid   = blockIdx.x * 256 + threadIdx.x;   // 0..32767
    const int lane  = gid & 63;
    const int ntk   = gid >> 6;
    const int nt    = ntk & 3;
    const int kstep = ntk >> 2;
    const int e  = nt * 16 + (lane & 15);
    const int k0 = kstep * 32 + (lane >> 4) * 8;

    const float* src = W + (size_t)e * D_MODEL + k0;
    float4 w0 = *(const float4*)(src);
    float4 w1 = *(const float4*)(src + 4);
    float wv[8] = {w0.x, w0.y, w0.z, w0.w, w1.x, w1.y, w1.z, w1.w};

    half8 hh, ll;
    #pragma unroll
    for (int j = 0; j < 8; ++j) {
        float ws = wv[j] * 64.0f;
        _Float16 h = (_Float16)ws;
        hh[j] = h;
        ll[j] = (_Float16)((ws - (float)h) * 4096.0f);
    }
    *(half8*)(whf + (size_t)gid * 8) = hh;
    *(half8*)(wlf + (size_t)gid * 8) = ll;
}

// global -> LDS direct (16B/lane, dest = wave-uniform base + lane*16)
#define GLD16(gp, lp) __builtin_amdgcn_global_load_lds( \
    (const __attribute__((address_space(1))) unsigned int*)(const void*)(gp), \
    (__attribute__((address_space(3))) unsigned int*)(void*)(lp), 16, 0, 0)

__device__ __forceinline__ void cvt_hilo(const float4 a, const float4 b,
                                         half8& hi, half8& lo) {
    float av[8] = {a.x, a.y, a.z, a.w, b.x, b.y, b.z, b.w};
    #pragma unroll
    for (int j = 0; j < 8; ++j) {
        _Float16 h = (_Float16)av[j];
        hi[j] = h;
        lo[j] = (_Float16)((av[j] - (float)h) * 4096.0f);
    }
}

// ---------------------------------------------------------------------------
// Main: 256 thr = 4 waves x 16 tokens, 512 blocks (2/CU). Groups of 2 ksteps
// (64 groups). BOTH A and B staged via global_load_lds, double-buffered:
//  - A: per wave, 4 slab-loads/group; lane l -> row 4s+(l>>4), 16B chunk
//    (l&15): each row read as contiguous 256B (coalesced, 16x fewer reqs
//    than the old per-lane fragment gather). Slab stride 1040B makes the
//    fragment ds_reads conflict-free (granule class (s+2q')%8 uniform).
//  - B: wave w stages (ksl=w&1, hi/lo=w>>1), nt=0..3, lane-linear.
// LDS = 33280 + 32768 = 66048 B -> 2 blocks/CU. Stages issue at group
// start, age ~1 group (~900cyc) before the barrier's vmcnt drain.
// ---------------------------------------------------------------------------
__global__ __launch_bounds__(256, 2)
void router_kernel(const float* __restrict__ x,
                   const _Float16* __restrict__ whf,
                   const _Float16* __restrict__ wlf,
                   float* __restrict__ out, int ntok) {
    __shared__ __align__(16) float     sA[2 * 4 * 4 * 260];   // [buf][wave][slab][260f]
    __shared__ __align__(16) _Float16  sB[2][2][2][4][512];   // [buf][ksl][h/l][nt][512]

    const int tid  = threadIdx.x;
    const int w    = tid >> 6;
    const int l    = tid & 63;
    const int tok0 = blockIdx.x * 64;

    // A stage sources: slab s, lane l -> row 4s+(l>>4), byte (l&15)*16 of the
    // group's 256B row-span
    const float* asrc0 = x + (size_t)(tok0 + w * 16 + 0 + (l >> 4)) * D_MODEL + (l & 15) * 4;
    const float* asrc1 = asrc0 + (size_t)4 * D_MODEL;
    const float* asrc2 = asrc0 + (size_t)8 * D_MODEL;
    const float* asrc3 = asrc0 + (size_t)12 * D_MODEL;
    // B stage source: wave w handles ksl=w&1, array w>>1
    const _Float16* bsrc = (w >> 1) ? wlf : whf;

    f32x4 hh[4], cc[4];
    #pragma unroll
    for (int nt = 0; nt < 4; ++nt) { hh[nt] = (f32x4)0.0f; cc[nt] = (f32x4)0.0f; }

#define STAGE(G, B)                                                            \
    {                                                                          \
        const int kf = (G) * 64;   /* float offset within row */               \
        GLD16(asrc0 + kf, &sA[(((B) * 4 + w) * 4 + 0) * 260]);                 \
        GLD16(asrc1 + kf, &sA[(((B) * 4 + w) * 4 + 1) * 260]);                 \
        GLD16(asrc2 + kf, &sA[(((B) * 4 + w) * 4 + 2) * 260]);                 \
        GLD16(asrc3 + kf, &sA[(((B) * 4 + w) * 4 + 3) * 260]);                 \
        const int kst = (G) * 2 + (w & 1);                                     \
        const size_t bo = (size_t)(kst * 4) * 512 + (size_t)l * 8;             \
        _Pragma("unroll")                                                      \
        for (int nt = 0; nt < 4; ++nt)                                         \
            GLD16(bsrc + bo + nt * 512, &sB[B][w & 1][w >> 1][nt][0]);         \
    }

#define STEP(KSL, CUR)                                                         \
    {                                                                          \
        const float* ap = &sA[(((CUR) * 4 + w) * 4 + ((l & 15) >> 2)) * 260    \
                              + ((l & 15) & 3) * 64 + (KSL) * 32 + (l >> 4) * 8]; \
        float4 a0 = *(const float4*)ap;                                        \
        float4 a1 = *(const float4*)(ap + 4);                                  \
        half8 ah, al;                                                          \
        cvt_hilo(a0, a1, ah, al);                                              \
        half8 bh[4], bl[4];                                                    \
        _Pragma("unroll")                                                      \
        for (int nt = 0; nt < 4; ++nt) {                                       \
            bh[nt] = *(const half8*)&sB[CUR][KSL][0][nt][l * 8];               \
            bl[nt] = *(const half8*)&sB[CUR][KSL][1][nt][l * 8];               \
        }                                                                      \
        _Pragma("unroll")                                                      \
        for (int nt = 0; nt < 4; ++nt)                                         \
            hh[nt] = __builtin_amdgcn_mfma_f32_16x16x32_f16(ah, bh[nt], hh[nt], 0, 0, 0); \
        _Pragma("unroll")                                                      \
        for (int nt = 0; nt < 4; ++nt)                                         \
            cc[nt] = __builtin_amdgcn_mfma_f32_16x16x32_f16(ah, bl[nt], cc[nt], 0, 0, 0); \
        _Pragma("unroll")                                                      \
        for (int nt = 0; nt < 4; ++nt)                                         \
            cc[nt] = __builtin_amdgcn_mfma_f32_16x16x32_f16(al, bh[nt], cc[nt], 0, 0, 0); \
    }

    // prologue: stage group 0 into buf 0
    STAGE(0, 0)
    __syncthreads();

    for (int gg = 0; gg < 32; ++gg) {
        const int g0 = gg * 2;
        // group g0 (buf 0): stage g0+1 into buf 1, compute, barrier
        STAGE(g0 + 1, 1)
        STEP(0, 0)
        STEP(1, 0)
        __syncthreads();
        // group g0+1 (buf 1): stage g0+2 into buf 0 (skip on last), compute
        if (g0 + 2 < 64) STAGE(g0 + 2, 0)
        STEP(0, 1)
        STEP(1, 1)
        __syncthreads();
    }
#undef STAGE
#undef STEP

    // logits = (hh + cc*2^-12) * 2^-6; top-2 over 16-lane butterfly
    float tt[4][4];   // [nt][q]
    #pragma unroll
    for (int nt = 0; nt < 4; ++nt) {
        f32x4 tot = (hh[nt] + cc[nt] * (1.0f / 4096.0f)) * (1.0f / 64.0f);
        tt[nt][0] = tot.x; tt[nt][1] = tot.y; tt[nt][2] = tot.z; tt[nt][3] = tot.w;
    }

    float* out_e = out + (size_t)2 * ntok;

    #pragma unroll
    for (int q = 0; q < 4; ++q) {
        // C/D layout: col = lane&15 (expert sub), row = (lane>>4)*4 + q (token)
        float v1 = -3.0e38f, v2 = -3.0e38f;
        int   i1 = 1 << 30,  i2 = 1 << 30;
        #pragma unroll
        for (int nt = 0; nt < 4; ++nt) {
            float v  = tt[nt][q];
            int   id = nt * 16 + (l & 15);
            if (v > v1 || (v == v1 && id < i1)) {
                v2 = v1; i2 = i1; v1 = v; i1 = id;
            } else if (v > v2 || (v == v2 && id < i2)) {
                v2 = v; i2 = id;
            }
        }
        #pragma unroll
        for (int m = 1; m < 16; m <<= 1) {
            float ov1 = __shfl_xor(v1, m, 64);
            int   oi1 = __shfl_xor(i1, m, 64);
            float ov2 = __shfl_xor(v2, m, 64);
            int   oi2 = __shfl_xor(i2, m, 64);
            bool ofirst = (ov1 > v1) || (ov1 == v1 && oi1 < i1);
            if (ofirst) {
                bool s2 = (ov2 > v1) || (ov2 == v1 && oi2 < i1);
                v2 = s2 ? ov2 : v1;  i2 = s2 ? oi2 : i1;
                v1 = ov1;            i1 = oi1;
            } else {
                bool s2 = (ov1 > v2) || (ov1 == v2 && oi1 < i2);
                v2 = s2 ? ov1 : v2;  i2 = s2 ? oi1 : i2;
            }
        }

        if ((l & 15) == 0) {
            const int tok = tok0 + w * 16 + (l >> 4) * 4 + q;
            float e = expf(v2 - v1);     // <= 1
            float d = 1.0f + e;
            out[2 * tok + 0] = 1.0f / d;
            out[2 * tok + 1] = e / d;
            out_e[2 * tok + 0] = (float)i1;
            out_e[2 * tok + 1] = (float)i2;
        }
    }
}

extern "C" void kernel_launch(void* const* d_in, const int* in_sizes, int n_in,
                              void* d_out, int out_size, void* d_ws, size_t ws_size,
                              hipStream_t stream) {
    const float* x = (const float*)d_in[0];
    const float* W = (const float*)d_in[1];
    float* out = (float*)d_out;
    const int ntok = in_sizes[0] / D_MODEL;   // 32768

    _Float16* whf = (_Float16*)d_ws;                           // 512 KB
    _Float16* wlf = (_Float16*)d_ws + (size_t)N_EXP * D_MODEL; // 512 KB

    wprep_kernel<<<dim3(128), dim3(256), 0, stream>>>(W, whf, wlf);
    router_kernel<<<dim3(ntok / 64), dim3(256), 0, stream>>>(x, whf, wlf, out, ntok);
}